// Round 8
// baseline (828.947 us; speedup 1.0000x reference)
//
#include <hip/hip_runtime.h>
#include <hip/hip_bf16.h>
#include <stdint.h>

#define T_DIM 256
#define B_DIM 64
#define DICO  8192
#define EMB   256
#define LAT   256
#define M_DIM (T_DIM*B_DIM)   /* 16384 */

#define BM 64
#define BN 256
#define BK 64
#define KSPLIT 2
#define KCHUNK (DICO/KSPLIT)  /* 4096 */
#define NKS (KCHUNK/BK)       /* 64 */

typedef short  bf16x8 __attribute__((ext_vector_type(8)));
typedef float  f32x4  __attribute__((ext_vector_type(4)));
typedef _Float16 f16x2 __attribute__((ext_vector_type(2)));

__device__ __forceinline__ ushort f2bf(float f) {
  uint32_t u = __float_as_uint(f);
  u += 0x7FFFu + ((u >> 16) & 1u);     // round-to-nearest-even
  return (ushort)(u >> 16);
}

__device__ __forceinline__ uint32_t cvtpk(float lo, float hi) {
  uint32_t r;
  asm("v_cvt_pk_bf16_f32 %0, %1, %2" : "=v"(r) : "v"(lo), "v"(hi));
  return r;
}

__device__ __forceinline__ void glds16(const void* g, void* l) {
  __builtin_amdgcn_global_load_lds(
      (const __attribute__((address_space(1))) uint32_t*)g,
      (__attribute__((address_space(3))) uint32_t*)l, 16, 0, 0);
}

// ---------------- Kernel 1: Wct[n][k] = sum_e W_emb[k][e] * W_enc[e][n], bf16, n-major
__global__ void wct_kernel(const float* __restrict__ Wemb, const float* __restrict__ Wenc,
                           ushort* __restrict__ wct) {
  const int n  = threadIdx.x;          // 0..255
  const int d0 = blockIdx.x * 32;      // 256 blocks
  __shared__ float we[32 * 256];
  __shared__ float tr[32 * 257];
  #pragma unroll
  for (int r = 0; r < 32; ++r) we[r*256 + n] = Wemb[(size_t)(d0 + r)*EMB + n];
  __syncthreads();
  float acc[32];
  #pragma unroll
  for (int d = 0; d < 32; ++d) acc[d] = 0.f;
  #pragma unroll 4
  for (int e = 0; e < 256; ++e) {
    float wv = Wenc[e*LAT + n];
    #pragma unroll
    for (int d = 0; d < 32; ++d) acc[d] += we[d*256 + e] * wv;   // LDS broadcast
  }
  #pragma unroll
  for (int d = 0; d < 32; ++d) tr[d*257 + n] = acc[d];
  __syncthreads();
  const int nn0 = n >> 2, kc = n & 3;
  #pragma unroll
  for (int p = 0; p < 4; ++p) {
    int nn = p*64 + nn0;
    bf16x8 v;
    #pragma unroll
    for (int j = 0; j < 8; ++j) v[j] = (short)f2bf(tr[(kc*8 + j)*257 + nn]);
    *(bf16x8*)(wct + (size_t)nn*DICO + d0 + kc*8) = v;
  }
}

// ---------------- Kernel 2 (R7, byte-frozen): xp_part[ksp] = x @ Wc
__global__ void __launch_bounds__(256, 2) gemm_kernel(const float* __restrict__ x,
                                                      const ushort* __restrict__ wct,
                                                      float* __restrict__ xp) {
  __shared__ __align__(16) ushort sA[2][BM * BK];   // 2 x 8 KB
  __shared__ __align__(16) ushort sB[2][BN * BK];   // 2 x 32 KB
  const int tid = threadIdx.x;
  const int bid = blockIdx.x;                        // 512 blocks
  const int swzb = (bid & 7) * 64 + (bid >> 3);
  const int mt = swzb & 255, ksp = swzb >> 8;
  const size_t rowbase = (size_t)mt * BM;
  const int kbase = ksp * KCHUNK;

  const int lane = tid & 63, wid = tid >> 6;
  const int l15 = lane & 15, lc = lane >> 4;

  const int r0 = tid >> 2, c0 = tid & 3;
  const float* ag = x + (rowbase + r0) * (size_t)DICO + kbase + c0 * 16;
  const int sx0 = (((2*c0    ) ^ (r0 & 7)) * 16);
  const int sx1 = (((2*c0 + 1) ^ (r0 & 7)) * 16);

  const int sw0 = (((    lc) ^ (l15 & 7)) * 16);
  const int sw1 = (((4 + lc) ^ (l15 & 7)) * 16);

  const char* wb = (const char*)wct;
  const size_t kb2 = (size_t)kbase * 2;

  const int brow_s = (tid >> 3);
  const int bslot_s = tid & 7;

  f32x4 acc[4][4];
  #pragma unroll
  for (int m = 0; m < 4; ++m)
    #pragma unroll
    for (int n = 0; n < 4; ++n) acc[m][n] = (f32x4){0.f, 0.f, 0.f, 0.f};

  float4 avP[4], avQ[4];

  auto stageB = [&](int buf, int kofs) {
    #pragma unroll
    for (int r = 0; r < 8; ++r) {
      const int row = r * 32 + brow_s;
      const int srcslot = bslot_s ^ (row & 7);
      glds16(wb + (size_t)row * (DICO * 2) + kb2 + (size_t)kofs * 2 + srcslot * 16,
             (char*)&sB[buf][0] + r * 4096 + tid * 16);
    }
  };
  auto storeA = [&](int buf, const float4* av) {
    const float4 a0 = av[0], a1 = av[1], a2 = av[2], a3 = av[3];
    bf16x8 w0, w1;
    w0[0]=(short)f2bf(a0.x); w0[1]=(short)f2bf(a0.y); w0[2]=(short)f2bf(a0.z); w0[3]=(short)f2bf(a0.w);
    w0[4]=(short)f2bf(a1.x); w0[5]=(short)f2bf(a1.y); w0[6]=(short)f2bf(a1.z); w0[7]=(short)f2bf(a1.w);
    w1[0]=(short)f2bf(a2.x); w1[1]=(short)f2bf(a2.y); w1[2]=(short)f2bf(a2.z); w1[3]=(short)f2bf(a2.w);
    w1[4]=(short)f2bf(a3.x); w1[5]=(short)f2bf(a3.y); w1[6]=(short)f2bf(a3.z); w1[7]=(short)f2bf(a3.w);
    char* base = (char*)&sA[buf][0] + r0 * 128;
    *(bf16x8*)(base + sx0) = w0;
    *(bf16x8*)(base + sx1) = w1;
  };
  auto compute = [&](int buf) {
    bf16x8 bfr[4][2];
    #pragma unroll
    for (int n = 0; n < 4; ++n) {
      const char* bb = (const char*)&sB[buf][0] + (wid*64 + n*16 + l15) * 128;
      bfr[n][0] = *(const bf16x8*)(bb + sw0);
      bfr[n][1] = *(const bf16x8*)(bb + sw1);
    }
    #pragma unroll
    for (int m = 0; m < 4; ++m) {
      const char* ab = (const char*)&sA[buf][0] + (m*16 + l15) * 128;
      bf16x8 a0 = *(const bf16x8*)(ab + sw0);
      bf16x8 a1 = *(const bf16x8*)(ab + sw1);
      #pragma unroll
      for (int n = 0; n < 4; ++n) {
        acc[m][n] = __builtin_amdgcn_mfma_f32_16x16x32_bf16(a0, bfr[n][0], acc[m][n], 0, 0, 0);
        acc[m][n] = __builtin_amdgcn_mfma_f32_16x16x32_bf16(a1, bfr[n][1], acc[m][n], 0, 0, 0);
      }
    }
  };

  auto body = [&](int k, float4* avC, float4* avL) {
    const int p = k & 1;
    const int kB = (k + 1 < NKS ? k + 1 : NKS - 1) * BK;
    const int kA = (k + 2 < NKS ? k + 2 : NKS - 1) * BK;
    stageB(p ^ 1, kB);
    asm volatile("" ::: "memory");
    #pragma unroll
    for (int q = 0; q < 4; ++q) avL[q] = *(const float4*)(ag + kA + q * 4);
    storeA(p ^ 1, avC);
    compute(p);
    asm volatile("s_waitcnt vmcnt(4)" ::: "memory");
    asm volatile("s_waitcnt lgkmcnt(0)" ::: "memory");
    __builtin_amdgcn_s_barrier();
    __builtin_amdgcn_sched_barrier(0);
  };

  stageB(0, 0);
  #pragma unroll
  for (int q = 0; q < 4; ++q) avP[q] = *(const float4*)(ag + 0   + q * 4);
  #pragma unroll
  for (int q = 0; q < 4; ++q) avQ[q] = *(const float4*)(ag + BK  + q * 4);
  storeA(0, avP);
  __syncthreads();

  for (int k = 0; k < NKS; k += 2) {
    body(k,     avQ, avP);
    body(k + 1, avP, avQ);
  }

  float* xpo = xp + ((size_t)ksp * M_DIM + rowbase) * LAT;
  #pragma unroll
  for (int m = 0; m < 4; ++m)
    #pragma unroll
    for (int n = 0; n < 4; ++n)
      #pragma unroll
      for (int j = 0; j < 4; ++j)
        xpo[(size_t)(m*16 + lc*4 + j) * LAT + wid*64 + n*16 + l15] = acc[m][n][j];
}

// ---------------- Kernel 2b (NEW, measured in isolation via delta-T):
// 128x128 tile, 2 blk/CU (64 KB LDS), ONE barrier/K-step, counted vmcnt(8)
// (8 A-loads issued 2 steps ahead stay in flight), coalesced 256B-per-row
// A-loads, cvt_pk staging, XOR-involution LDS. Writes to scratch xp2.
__global__ void __launch_bounds__(256, 2) gemm2_kernel(const float* __restrict__ x,
                                                       const ushort* __restrict__ wct,
                                                       float* __restrict__ xp) {
  __shared__ __align__(16) ushort sA[2][128 * 64];  // 2 x 16 KB
  __shared__ __align__(16) ushort sB[2][128 * 64];  // 2 x 16 KB
  const int tid = threadIdx.x;
  const int bid = blockIdx.x;                        // 512 blocks
  const int swzb = (bid & 7) * 64 + (bid >> 3);      // XCD-contiguous
  const int mt  = swzb & 127;                        // 128 M-tiles
  const int nt  = (swzb >> 7) & 1;                   // 2 N-tiles (uniform per XCD)
  const int ksp = swzb >> 8;                         // 2 K-splits (uniform per XCD)
  const size_t rowbase = (size_t)mt * 128;
  const int kbase = ksp * KCHUNK;

  const int lane = tid & 63, wid = tid >> 6;
  const int l15 = lane & 15, lc = lane >> 4;
  const int wr = wid >> 1, wc = wid & 1;             // 2x2 wave grid, 64x64 each

  // A staging: pass p (0..7): row = p*16 + ar, 16B chunk ac (256B contiguous/row)
  const int ar = tid >> 4, ac = tid & 15;
  const float* ag = x + (rowbase + ar) * (size_t)DICO + kbase + ac * 4;
  // LDS dest (8B): slot = (ac>>1) ^ (row&7), half = ac&1; row&7 == ar&7
  const int awb = (((ac >> 1) ^ (ar & 7)) * 16) + (ac & 1) * 8;

  const int sw0 = (((    lc) ^ (l15 & 7)) * 16);
  const int sw1 = (((4 + lc) ^ (l15 & 7)) * 16);

  const char* wb = (const char*)wct;
  const size_t kb2 = (size_t)kbase * 2;
  const int nrow0 = nt * 128;

  const int brow_s = tid >> 3, bslot_s = tid & 7;

  f32x4 acc[4][4];
  #pragma unroll
  for (int m = 0; m < 4; ++m)
    #pragma unroll
    for (int n = 0; n < 4; ++n) acc[m][n] = (f32x4){0.f, 0.f, 0.f, 0.f};

  float4 avP[8], avQ[8];

  auto loadA = [&](float4* av, int kofs) {
    #pragma unroll
    for (int p = 0; p < 8; ++p)
      av[p] = *(const float4*)(ag + (size_t)(p * 16) * DICO + kofs);
  };
  auto stageB = [&](int buf, int kofs) {
    #pragma unroll
    for (int r = 0; r < 4; ++r) {
      const int row = r * 32 + brow_s;
      const int srcslot = bslot_s ^ (row & 7);
      glds16(wb + (size_t)(nrow0 + row) * (DICO * 2) + kb2 + (size_t)kofs * 2 + srcslot * 16,
             (char*)&sB[buf][0] + r * 8192 + tid * 16);
    }
  };
  auto storeA = [&](int buf, const float4* av) {
    #pragma unroll
    for (int p = 0; p < 8; ++p) {
      uint2 d;
      d.x = cvtpk(av[p].x, av[p].y);
      d.y = cvtpk(av[p].z, av[p].w);
      *(uint2*)((char*)&sA[buf][0] + (p * 16 + ar) * 128 + awb) = d;
    }
  };
  auto compute = [&](int buf) {
    bf16x8 bfr[4][2];
    #pragma unroll
    for (int n = 0; n < 4; ++n) {
      const char* bb = (const char*)&sB[buf][0] + (wc*64 + n*16 + l15) * 128;
      bfr[n][0] = *(const bf16x8*)(bb + sw0);
      bfr[n][1] = *(const bf16x8*)(bb + sw1);
    }
    #pragma unroll
    for (int m = 0; m < 4; ++m) {
      const char* ab = (const char*)&sA[buf][0] + (wr*64 + m*16 + l15) * 128;
      bf16x8 a0 = *(const bf16x8*)(ab + sw0);
      bf16x8 a1 = *(const bf16x8*)(ab + sw1);
      #pragma unroll
      for (int n = 0; n < 4; ++n) {
        acc[m][n] = __builtin_amdgcn_mfma_f32_16x16x32_bf16(a0, bfr[n][0], acc[m][n], 0, 0, 0);
        acc[m][n] = __builtin_amdgcn_mfma_f32_16x16x32_bf16(a1, bfr[n][1], acc[m][n], 0, 0, 0);
      }
    }
  };

  auto body = [&](int k, float4* avC, float4* avL) {
    const int p = k & 1;
    const int kB = (k + 1 < NKS ? k + 1 : NKS - 1) * BK;
    const int kA = (k + 2 < NKS ? k + 2 : NKS - 1) * BK;
    stageB(p ^ 1, kB);                                // 4 glds (oldest)
    asm volatile("" ::: "memory");
    loadA(avL, kA);                                   // 8 loads (newest)
    asm volatile("" ::: "memory");
    storeA(p ^ 1, avC);                               // waits A(k+1) regs only
    compute(p);
    asm volatile("s_waitcnt vmcnt(8)" ::: "memory");  // drain 4 B-glds; 8 A fly on
    asm volatile("s_waitcnt lgkmcnt(0)" ::: "memory");
    __builtin_amdgcn_s_barrier();                     // ONE barrier per step
    __builtin_amdgcn_sched_barrier(0);
  };

  // prologue
  stageB(0, 0);
  asm volatile("" ::: "memory");
  loadA(avP, 0);
  asm volatile("" ::: "memory");
  loadA(avQ, BK);
  storeA(0, avP);
  __syncthreads();                                    // one-time full drain

  for (int k = 0; k < NKS; k += 2) {
    body(k,     avQ, avP);
    body(k + 1, avP, avQ);
  }

  float* xpo = xp + ((size_t)ksp * M_DIM + rowbase) * LAT + nrow0;
  #pragma unroll
  for (int m = 0; m < 4; ++m)
    #pragma unroll
    for (int n = 0; n < 4; ++n)
      #pragma unroll
      for (int j = 0; j < 4; ++j)
        xpo[(size_t)(wr*64 + m*16 + lc*4 + j) * LAT + wc*64 + n*16 + l15] = acc[m][n][j];
}

// ---------------- Kernel 3 (byte-frozen): per-b recurrence h = tanh(xp_t + bc + h@Wh)
__global__ void __launch_bounds__(256, 1) rnn_kernel(const float* __restrict__ xp,
                           const float* __restrict__ h0, const float* __restrict__ Wenc,
                           const float* __restrict__ bemb, const float* __restrict__ benc,
                           float* __restrict__ out) {
  const int b = blockIdx.x, l = threadIdx.x;       // 64 blocks x 256 threads
  __shared__ __align__(16) uint32_t hbuf[2][128];  // double-buffered h (f16)
  float bc = benc[l];
  #pragma unroll 8
  for (int e = 0; e < 256; ++e) bc += bemb[e] * Wenc[e*LAT + l];
  f16x2 wh[128];
  #pragma unroll
  for (int j = 0; j < 128; ++j) {
    f16x2 w;
    w[0] = (_Float16)Wenc[(size_t)(EMB + 2*j    )*LAT + l];
    w[1] = (_Float16)Wenc[(size_t)(EMB + 2*j + 1)*LAT + l];
    wh[j] = w;
  }
  ((_Float16*)&hbuf[0][0])[l] = (_Float16)h0[(size_t)b*LAT + l];
  __syncthreads();                                 // one-time full drain (prologue)
  const float* xpb = xp + (size_t)b*LAT + l;
  float*       ob  = out + (size_t)b*LAT + l;
  const size_t ST = (size_t)B_DIM * LAT;           // 16384
  const size_t PO = (size_t)M_DIM * LAT;           // partial offset
  float xa0 = xpb[0],  xa1 = xpb[PO];
  float xb0 = xpb[ST], xb1 = xpb[ST + PO];
  float xc0 = 0.f, xc1 = 0.f;
  for (int t = 0; t < T_DIM; ++t) {
    if (t + 2 < T_DIM) {
      size_t ni = (size_t)(t + 2) * ST;
      xc0 = xpb[ni]; xc1 = xpb[ni + PO];           // stays in flight across barriers
    }
    const uint32_t* hc = &hbuf[t & 1][0];
    float s0=0.f,s1=0.f,s2=0.f,s3=0.f,s4=0.f,s5=0.f,s6=0.f,s7=0.f;
    #pragma unroll
    for (int q = 0; q < 16; ++q) {
      uint4 hv0 = *(const uint4*)(hc + q*8);       // LDS broadcast (uniform addr)
      uint4 hv1 = *(const uint4*)(hc + q*8 + 4);
      s0 = __builtin_amdgcn_fdot2(wh[q*8+0], __builtin_bit_cast(f16x2, hv0.x), s0, false);
      s1 = __builtin_amdgcn_fdot2(wh[q*8+1], __builtin_bit_cast(f16x2, hv0.y), s1, false);
      s2 = __builtin_amdgcn_fdot2(wh[q*8+2], __builtin_bit_cast(f16x2, hv0.z), s2, false);
      s3 = __builtin_amdgcn_fdot2(wh[q*8+3], __builtin_bit_cast(f16x2, hv0.w), s3, false);
      s4 = __builtin_amdgcn_fdot2(wh[q*8+4], __builtin_bit_cast(f16x2, hv1.x), s4, false);
      s5 = __builtin_amdgcn_fdot2(wh[q*8+5], __builtin_bit_cast(f16x2, hv1.y), s5, false);
      s6 = __builtin_amdgcn_fdot2(wh[q*8+6], __builtin_bit_cast(f16x2, hv1.z), s6, false);
      s7 = __builtin_amdgcn_fdot2(wh[q*8+7], __builtin_bit_cast(f16x2, hv1.w), s7, false);
    }
    float pre = (xa0 + xa1) + bc + (((s0+s1)+(s2+s3)) + ((s4+s5)+(s6+s7)));
    float ax = fabsf(pre);
    float e2 = __expf(-2.f * ax);
    float r  = __fdividef(1.f - e2, 1.f + e2);
    float hn = (pre < 0.f) ? -r : r;
    ob[(size_t)t * ST] = hn;                       // fire-and-forget (not drained)
    ((_Float16*)&hbuf[(t + 1) & 1][0])[l] = (_Float16)hn;
    __builtin_amdgcn_sched_barrier(0);
    asm volatile("s_waitcnt lgkmcnt(0)" ::: "memory");   // LDS write visible
    __builtin_amdgcn_s_barrier();                        // vmcnt NOT drained
    __builtin_amdgcn_sched_barrier(0);
    xa0 = xb0; xa1 = xb1; xb0 = xc0; xb1 = xc1;
  }
}

extern "C" void kernel_launch(void* const* d_in, const int* in_sizes, int n_in,
                              void* d_out, int out_size, void* d_ws, size_t ws_size,
                              hipStream_t stream) {
  const float* x    = (const float*)d_in[0];
  const float* h0   = (const float*)d_in[1];
  const float* Wemb = (const float*)d_in[2];
  const float* bemb = (const float*)d_in[3];
  const float* Wenc = (const float*)d_in[4];
  const float* benc = (const float*)d_in[5];
  float* out = (float*)d_out;

  ushort* wct = (ushort*)d_ws;                               // 4 MiB bf16 [256][8192]
  float*  xp  = (float*)((char*)d_ws + ((size_t)4  << 20));  // 2 x 16 MiB fp32 partials
  float*  xp2 = (float*)((char*)d_ws + ((size_t)40 << 20));  // gemm2 scratch (unused)

  wct_kernel<<<256, 256, 0, stream>>>(Wemb, Wenc, wct);
  gemm_kernel<<<512, 256, 0, stream>>>(x, wct, xp);
  gemm2_kernel<<<512, 256, 0, stream>>>(x, wct, xp2);        // timing probe: dT = g2
  rnn_kernel<<<64, 256, 0, stream>>>(xp, h0, Wenc, bemb, benc, out);
}

// Round 9
// 731.668 us; speedup vs baseline: 1.1330x; 1.1330x over previous
//
#include <hip/hip_runtime.h>
#include <hip/hip_bf16.h>
#include <stdint.h>

#define T_DIM 256
#define B_DIM 64
#define DICO  8192
#define EMB   256
#define LAT   256
#define M_DIM (T_DIM*B_DIM)   /* 16384 */

#define BK 64
#define KSPLIT 2
#define KCHUNK (DICO/KSPLIT)  /* 4096 */
#define NKS (KCHUNK/BK)       /* 64 */

typedef short  bf16x8 __attribute__((ext_vector_type(8)));
typedef float  f32x4  __attribute__((ext_vector_type(4)));
typedef _Float16 f16x8 __attribute__((ext_vector_type(8)));

__device__ __forceinline__ ushort f2bf(float f) {
  uint32_t u = __float_as_uint(f);
  u += 0x7FFFu + ((u >> 16) & 1u);     // round-to-nearest-even
  return (ushort)(u >> 16);
}

__device__ __forceinline__ uint32_t cvtpk(float lo, float hi) {
  uint32_t r;
  asm("v_cvt_pk_bf16_f32 %0, %1, %2" : "=v"(r) : "v"(lo), "v"(hi));
  return r;
}

__device__ __forceinline__ void glds16(const void* g, void* l) {
  __builtin_amdgcn_global_load_lds(
      (const __attribute__((address_space(1))) uint32_t*)g,
      (__attribute__((address_space(3))) uint32_t*)l, 16, 0, 0);
}

// ---------------- Kernel 1: Wct[n][k] = sum_e W_emb[k][e] * W_enc[e][n], bf16, n-major
__global__ void wct_kernel(const float* __restrict__ Wemb, const float* __restrict__ Wenc,
                           ushort* __restrict__ wct) {
  const int n  = threadIdx.x;          // 0..255
  const int d0 = blockIdx.x * 32;      // 256 blocks
  __shared__ float we[32 * 256];
  __shared__ float tr[32 * 257];
  #pragma unroll
  for (int r = 0; r < 32; ++r) we[r*256 + n] = Wemb[(size_t)(d0 + r)*EMB + n];
  __syncthreads();
  float acc[32];
  #pragma unroll
  for (int d = 0; d < 32; ++d) acc[d] = 0.f;
  #pragma unroll 4
  for (int e = 0; e < 256; ++e) {
    float wv = Wenc[e*LAT + n];
    #pragma unroll
    for (int d = 0; d < 32; ++d) acc[d] += we[d*256 + e] * wv;   // LDS broadcast
  }
  #pragma unroll
  for (int d = 0; d < 32; ++d) tr[d*257 + n] = acc[d];
  __syncthreads();
  const int nn0 = n >> 2, kc = n & 3;
  #pragma unroll
  for (int p = 0; p < 4; ++p) {
    int nn = p*64 + nn0;
    bf16x8 v;
    #pragma unroll
    for (int j = 0; j < 8; ++j) v[j] = (short)f2bf(tr[(kc*8 + j)*257 + nn]);
    *(bf16x8*)(wct + (size_t)nn*DICO + d0 + kc*8) = v;
  }
}

// ---------------- Kernel 2: xp_part[ksp] = x @ Wc  (gemm2, bug-fixed, now primary)
// 128x128 tile, 2 blk/CU (64 KB LDS), ONE raw barrier/K-step, counted vmcnt(8)
// (8 A-loads issued 2 steps ahead stay in flight), 256B-contiguous A-loads,
// cvt_pk staging, XOR-involution LDS.  FIX vs R8 probe: stageB dest stride
// r*4096 (256 thr x 16B = 4KB/round) -- R8's r*8192 mismatched rows & overflowed.
__global__ void __launch_bounds__(256, 2) gemm2_kernel(const float* __restrict__ x,
                                                       const ushort* __restrict__ wct,
                                                       float* __restrict__ xp) {
  __shared__ __align__(16) ushort sA[2][128 * 64];  // 2 x 16 KB
  __shared__ __align__(16) ushort sB[2][128 * 64];  // 2 x 16 KB
  const int tid = threadIdx.x;
  const int bid = blockIdx.x;                        // 512 blocks
  const int swzb = (bid & 7) * 64 + (bid >> 3);      // XCD-contiguous
  const int mt  = swzb & 127;                        // 128 M-tiles
  const int nt  = (swzb >> 7) & 1;                   // N-half (uniform per XCD)
  const int ksp = swzb >> 8;                         // K-split (uniform per XCD)
  const size_t rowbase = (size_t)mt * 128;
  const int kbase = ksp * KCHUNK;

  const int lane = tid & 63, wid = tid >> 6;
  const int l15 = lane & 15, lc = lane >> 4;
  const int wr = wid >> 1, wc = wid & 1;             // 2x2 wave grid, 64x64 each

  // A staging: pass p (0..7): row = p*16 + ar, 16B chunk ac (256B contiguous/row)
  const int ar = tid >> 4, ac = tid & 15;            // ar 0..15, ac 0..15
  const float* ag = x + (rowbase + ar) * (size_t)DICO + kbase + ac * 4;
  // LDS dest (8B): slot = (ac>>1) ^ (row&7), half = ac&1; row&7 == ar&7
  const int awb = (((ac >> 1) ^ (ar & 7)) * 16) + (ac & 1) * 8;

  const int sw0 = (((    lc) ^ (l15 & 7)) * 16);
  const int sw1 = (((4 + lc) ^ (l15 & 7)) * 16);

  const char* wb = (const char*)wct;
  const size_t kb2 = (size_t)kbase * 2;
  const int nrow0 = nt * 128;

  const int brow_s = tid >> 3, bslot_s = tid & 7;    // brow_s 0..31

  f32x4 acc[4][4];
  #pragma unroll
  for (int m = 0; m < 4; ++m)
    #pragma unroll
    for (int n = 0; n < 4; ++n) acc[m][n] = (f32x4){0.f, 0.f, 0.f, 0.f};

  float4 avP[8], avQ[8];

  auto loadA = [&](float4* av, int kofs) {
    #pragma unroll
    for (int p = 0; p < 8; ++p)
      av[p] = *(const float4*)(ag + (size_t)(p * 16) * DICO + kofs);
  };
  auto stageB = [&](int buf, int kofs) {
    #pragma unroll
    for (int r = 0; r < 4; ++r) {
      const int row = r * 32 + brow_s;               // 0..127
      const int srcslot = bslot_s ^ (row & 7);
      glds16(wb + (size_t)(nrow0 + row) * (DICO * 2) + kb2 + (size_t)kofs * 2 + srcslot * 16,
             (char*)&sB[buf][0] + r * 4096 + tid * 16);   // dest row = r*32 + tid>>3  (FIXED)
    }
  };
  auto storeA = [&](int buf, const float4* av) {
    #pragma unroll
    for (int p = 0; p < 8; ++p) {
      uint2 d;
      d.x = cvtpk(av[p].x, av[p].y);
      d.y = cvtpk(av[p].z, av[p].w);
      *(uint2*)((char*)&sA[buf][0] + (p * 16 + ar) * 128 + awb) = d;
    }
  };
  auto compute = [&](int buf) {
    bf16x8 bfr[4][2];
    #pragma unroll
    for (int n = 0; n < 4; ++n) {
      const char* bb = (const char*)&sB[buf][0] + (wc*64 + n*16 + l15) * 128;
      bfr[n][0] = *(const bf16x8*)(bb + sw0);
      bfr[n][1] = *(const bf16x8*)(bb + sw1);
    }
    #pragma unroll
    for (int m = 0; m < 4; ++m) {
      const char* ab = (const char*)&sA[buf][0] + (wr*64 + m*16 + l15) * 128;
      bf16x8 a0 = *(const bf16x8*)(ab + sw0);
      bf16x8 a1 = *(const bf16x8*)(ab + sw1);
      #pragma unroll
      for (int n = 0; n < 4; ++n) {
        acc[m][n] = __builtin_amdgcn_mfma_f32_16x16x32_bf16(a0, bfr[n][0], acc[m][n], 0, 0, 0);
        acc[m][n] = __builtin_amdgcn_mfma_f32_16x16x32_bf16(a1, bfr[n][1], acc[m][n], 0, 0, 0);
      }
    }
  };

  auto body = [&](int k, float4* avC, float4* avL) {
    const int p = k & 1;
    const int kB = (k + 1 < NKS ? k + 1 : NKS - 1) * BK;
    const int kA = (k + 2 < NKS ? k + 2 : NKS - 1) * BK;
    stageB(p ^ 1, kB);                                // 4 glds (oldest)
    asm volatile("" ::: "memory");
    loadA(avL, kA);                                   // 8 loads (newest)
    asm volatile("" ::: "memory");
    storeA(p ^ 1, avC);                               // waits A(k+1) regs only
    compute(p);
    asm volatile("s_waitcnt vmcnt(8)" ::: "memory");  // drain 4 B-glds; 8 A fly on
    asm volatile("s_waitcnt lgkmcnt(0)" ::: "memory");
    __builtin_amdgcn_s_barrier();                     // ONE barrier per step
    __builtin_amdgcn_sched_barrier(0);
  };

  stageB(0, 0);
  asm volatile("" ::: "memory");
  loadA(avP, 0);
  asm volatile("" ::: "memory");
  loadA(avQ, BK);
  storeA(0, avP);
  __syncthreads();                                    // one-time full drain

  for (int k = 0; k < NKS; k += 2) {
    body(k,     avQ, avP);
    body(k + 1, avP, avQ);
  }

  float* xpo = xp + ((size_t)ksp * M_DIM + rowbase) * LAT + nrow0;
  #pragma unroll
  for (int m = 0; m < 4; ++m)
    #pragma unroll
    for (int n = 0; n < 4; ++n)
      #pragma unroll
      for (int j = 0; j < 4; ++j)
        xpo[(size_t)(wr*64 + m*16 + lc*4 + j) * LAT + wc*64 + n*16 + l15] = acc[m][n][j];
}

// ---------------- Kernel 3: MFMA-batched RNN.  H_{t+1} = tanh(XP_t + H_t @ Wh)
// 4 blocks x 16 batches, 512 thr (8 waves).  Wave w owns latent cols [32w,32w+32):
// Wh B-fragments LIVE IN REGISTERS (64 VGPR/lane).  H (16x264-padded f16) double-
// buffered in LDS.  Per step/wave: 8 ds_read_b128 (A-frags) + 16 mfma_16x16x32_f16
// -> tanh -> out store (fire&forget) + H write -> lgkmcnt(0) + raw s_barrier
// (xp prefetch, 2 steps ahead, stays in flight).
__global__ void __launch_bounds__(512, 2) rnn_mfma_kernel(const float* __restrict__ xp,
                           const float* __restrict__ h0, const float* __restrict__ Wenc,
                           const float* __restrict__ bemb, const float* __restrict__ benc,
                           float* __restrict__ out) {
  const int tid = threadIdx.x;
  const int w = tid >> 6, lane = tid & 63;
  const int l15 = lane & 15, lc = lane >> 4;
  const int bb = blockIdx.x * 16;                  // batch base
  const int c0 = w*32 + l15, c1 = c0 + 16;         // latent cols (2 n-frags)
  const int rb = lc * 4;                           // C-row base (batch-local)

  __shared__ _Float16 hbuf[2][16 * 264];           // +8 f16 row pad: conflict-free b128

  // Wh fragments: whf{0,1}[ks][j] = Wh[ks*32 + lc*8 + j][c{0,1}]  (B-frag layout)
  f16x8 whf0[8], whf1[8];
  #pragma unroll
  for (int ks = 0; ks < 8; ++ks) {
    f16x8 w0, w1;
    #pragma unroll
    for (int j = 0; j < 8; ++j) {
      const int k = ks*32 + lc*8 + j;
      w0[j] = (_Float16)Wenc[(size_t)(EMB + k)*LAT + c0];
      w1[j] = (_Float16)Wenc[(size_t)(EMB + k)*LAT + c1];
    }
    whf0[ks] = w0; whf1[ks] = w1;
  }
  float bc0 = benc[c0], bc1 = benc[c1];
  for (int e = 0; e < 256; ++e) {
    float be = bemb[e];
    bc0 += be * Wenc[(size_t)e*LAT + c0];
    bc1 += be * Wenc[(size_t)e*LAT + c1];
  }
  #pragma unroll
  for (int j = 0; j < 4; ++j) {
    hbuf[0][(rb + j)*264 + c0] = (_Float16)h0[(size_t)(bb + rb + j)*LAT + c0];
    hbuf[0][(rb + j)*264 + c1] = (_Float16)h0[(size_t)(bb + rb + j)*LAT + c1];
  }
  __syncthreads();

  const size_t PO = (size_t)M_DIM * LAT;
  float xpP[16], xpQ[16];
  auto loadxp = [&](float* xb, int t) {
    #pragma unroll
    for (int j = 0; j < 4; ++j) {
      const size_t m = ((size_t)t*B_DIM + bb + rb + j) * LAT;
      xb[j*4 + 0] = xp[m + c0];
      xb[j*4 + 1] = xp[m + c0 + PO];
      xb[j*4 + 2] = xp[m + c1];
      xb[j*4 + 3] = xp[m + c1 + PO];
    }
  };
  loadxp(xpP, 0);
  loadxp(xpQ, 1);

  auto step = [&](int t, float* xb) {
    const _Float16* hc = &hbuf[t & 1][0];
    f32x4 acc0 = (f32x4){0.f,0.f,0.f,0.f};
    f32x4 acc1 = (f32x4){0.f,0.f,0.f,0.f};
    #pragma unroll
    for (int ks = 0; ks < 8; ++ks) {
      f16x8 a = *(const f16x8*)(hc + l15*264 + ks*32 + lc*8);   // plain read: compiler waits
      acc0 = __builtin_amdgcn_mfma_f32_16x16x32_f16(a, whf0[ks], acc0, 0, 0, 0);
      acc1 = __builtin_amdgcn_mfma_f32_16x16x32_f16(a, whf1[ks], acc1, 0, 0, 0);
    }
    _Float16* hn_ = &hbuf[(t + 1) & 1][0];
    float* ob = out + ((size_t)t*B_DIM + bb + rb) * LAT;
    #pragma unroll
    for (int j = 0; j < 4; ++j) {                    // C row = rb+j, cols c0/c1
      float p0 = acc0[j] + bc0 + xb[j*4+0] + xb[j*4+1];
      float p1 = acc1[j] + bc1 + xb[j*4+2] + xb[j*4+3];
      float a0 = fabsf(p0),        a1 = fabsf(p1);
      float e0 = __expf(-2.f*a0),  e1 = __expf(-2.f*a1);
      float r0 = __fdividef(1.f - e0, 1.f + e0);
      float r1 = __fdividef(1.f - e1, 1.f + e1);
      float h0v = (p0 < 0.f) ? -r0 : r0;
      float h1v = (p1 < 0.f) ? -r1 : r1;
      ob[(size_t)j*LAT + c0] = h0v;                  // fire-and-forget
      ob[(size_t)j*LAT + c1] = h1v;
      hn_[(rb + j)*264 + c0] = (_Float16)h0v;
      hn_[(rb + j)*264 + c1] = (_Float16)h1v;
    }
    const int tf = (t + 2 < T_DIM) ? t + 2 : T_DIM - 1;
    loadxp(xb, tf);                                  // refill consumed bank; flies across barrier
    __builtin_amdgcn_sched_barrier(0);
    asm volatile("s_waitcnt lgkmcnt(0)" ::: "memory");   // LDS reads+writes done
    __builtin_amdgcn_s_barrier();                        // vmcnt NOT drained
    __builtin_amdgcn_sched_barrier(0);
  };

  for (int t = 0; t < T_DIM; t += 2) {
    step(t,     xpP);
    step(t + 1, xpQ);
  }
}

extern "C" void kernel_launch(void* const* d_in, const int* in_sizes, int n_in,
                              void* d_out, int out_size, void* d_ws, size_t ws_size,
                              hipStream_t stream) {
  const float* x    = (const float*)d_in[0];
  const float* h0   = (const float*)d_in[1];
  const float* Wemb = (const float*)d_in[2];
  const float* bemb = (const float*)d_in[3];
  const float* Wenc = (const float*)d_in[4];
  const float* benc = (const float*)d_in[5];
  float* out = (float*)d_out;

  ushort* wct = (ushort*)d_ws;                               // 4 MiB bf16 [256][8192]
  float*  xp  = (float*)((char*)d_ws + ((size_t)4 << 20));   // 2 x 16 MiB fp32 partials

  wct_kernel<<<256, 256, 0, stream>>>(Wemb, Wenc, wct);
  gemm2_kernel<<<512, 256, 0, stream>>>(x, wct, xp);
  rnn_mfma_kernel<<<4, 512, 0, stream>>>(xp, h0, Wenc, bemb, benc, out);
}

// Round 10
// 714.809 us; speedup vs baseline: 1.1597x; 1.0236x over previous
//
#include <hip/hip_runtime.h>
#include <hip/hip_bf16.h>
#include <stdint.h>

#define T_DIM 256
#define B_DIM 64
#define DICO  8192
#define EMB   256
#define LAT   256
#define M_DIM (T_DIM*B_DIM)   /* 16384 */

#define BK 64
#define KSPLIT 2
#define KCHUNK (DICO/KSPLIT)  /* 4096 */
#define NKS (KCHUNK/BK)       /* 64 */

typedef short  bf16x8 __attribute__((ext_vector_type(8)));
typedef float  f32x4  __attribute__((ext_vector_type(4)));
typedef _Float16 f16x8 __attribute__((ext_vector_type(8)));

__device__ __forceinline__ ushort f2bf(float f) {
  uint32_t u = __float_as_uint(f);
  u += 0x7FFFu + ((u >> 16) & 1u);     // round-to-nearest-even
  return (ushort)(u >> 16);
}

__device__ __forceinline__ uint32_t cvtpk(float lo, float hi) {
  uint32_t r;
  asm("v_cvt_pk_bf16_f32 %0, %1, %2" : "=v"(r) : "v"(lo), "v"(hi));
  return r;
}

__device__ __forceinline__ void glds16(const void* g, void* l) {
  __builtin_amdgcn_global_load_lds(
      (const __attribute__((address_space(1))) uint32_t*)g,
      (__attribute__((address_space(3))) uint32_t*)l, 16, 0, 0);
}

// ---------------- Kernel 1 (byte-frozen): Wct[n][k] = sum_e W_emb[k][e] * W_enc[e][n]
__global__ void wct_kernel(const float* __restrict__ Wemb, const float* __restrict__ Wenc,
                           ushort* __restrict__ wct) {
  const int n  = threadIdx.x;          // 0..255
  const int d0 = blockIdx.x * 32;      // 256 blocks
  __shared__ float we[32 * 256];
  __shared__ float tr[32 * 257];
  #pragma unroll
  for (int r = 0; r < 32; ++r) we[r*256 + n] = Wemb[(size_t)(d0 + r)*EMB + n];
  __syncthreads();
  float acc[32];
  #pragma unroll
  for (int d = 0; d < 32; ++d) acc[d] = 0.f;
  #pragma unroll 4
  for (int e = 0; e < 256; ++e) {
    float wv = Wenc[e*LAT + n];
    #pragma unroll
    for (int d = 0; d < 32; ++d) acc[d] += we[d*256 + e] * wv;   // LDS broadcast
  }
  #pragma unroll
  for (int d = 0; d < 32; ++d) tr[d*257 + n] = acc[d];
  __syncthreads();
  const int nn0 = n >> 2, kc = n & 3;
  #pragma unroll
  for (int p = 0; p < 4; ++p) {
    int nn = p*64 + nn0;
    bf16x8 v;
    #pragma unroll
    for (int j = 0; j < 8; ++j) v[j] = (short)f2bf(tr[(kc*8 + j)*257 + nn]);
    *(bf16x8*)(wct + (size_t)nn*DICO + d0 + kc*8) = v;
  }
}

// ---------------- Kernel 2 (byte-frozen from R9): xp_part[ksp] = x @ Wc
__global__ void __launch_bounds__(256, 2) gemm2_kernel(const float* __restrict__ x,
                                                       const ushort* __restrict__ wct,
                                                       float* __restrict__ xp) {
  __shared__ __align__(16) ushort sA[2][128 * 64];  // 2 x 16 KB
  __shared__ __align__(16) ushort sB[2][128 * 64];  // 2 x 16 KB
  const int tid = threadIdx.x;
  const int bid = blockIdx.x;                        // 512 blocks
  const int swzb = (bid & 7) * 64 + (bid >> 3);      // XCD-contiguous
  const int mt  = swzb & 127;                        // 128 M-tiles
  const int nt  = (swzb >> 7) & 1;                   // N-half (uniform per XCD)
  const int ksp = swzb >> 8;                         // K-split (uniform per XCD)
  const size_t rowbase = (size_t)mt * 128;
  const int kbase = ksp * KCHUNK;

  const int lane = tid & 63, wid = tid >> 6;
  const int l15 = lane & 15, lc = lane >> 4;
  const int wr = wid >> 1, wc = wid & 1;             // 2x2 wave grid, 64x64 each

  const int ar = tid >> 4, ac = tid & 15;            // ar 0..15, ac 0..15
  const float* ag = x + (rowbase + ar) * (size_t)DICO + kbase + ac * 4;
  const int awb = (((ac >> 1) ^ (ar & 7)) * 16) + (ac & 1) * 8;

  const int sw0 = (((    lc) ^ (l15 & 7)) * 16);
  const int sw1 = (((4 + lc) ^ (l15 & 7)) * 16);

  const char* wb = (const char*)wct;
  const size_t kb2 = (size_t)kbase * 2;
  const int nrow0 = nt * 128;

  const int brow_s = tid >> 3, bslot_s = tid & 7;    // brow_s 0..31

  f32x4 acc[4][4];
  #pragma unroll
  for (int m = 0; m < 4; ++m)
    #pragma unroll
    for (int n = 0; n < 4; ++n) acc[m][n] = (f32x4){0.f, 0.f, 0.f, 0.f};

  float4 avP[8], avQ[8];

  auto loadA = [&](float4* av, int kofs) {
    #pragma unroll
    for (int p = 0; p < 8; ++p)
      av[p] = *(const float4*)(ag + (size_t)(p * 16) * DICO + kofs);
  };
  auto stageB = [&](int buf, int kofs) {
    #pragma unroll
    for (int r = 0; r < 4; ++r) {
      const int row = r * 32 + brow_s;               // 0..127
      const int srcslot = bslot_s ^ (row & 7);
      glds16(wb + (size_t)(nrow0 + row) * (DICO * 2) + kb2 + (size_t)kofs * 2 + srcslot * 16,
             (char*)&sB[buf][0] + r * 4096 + tid * 16);
    }
  };
  auto storeA = [&](int buf, const float4* av) {
    #pragma unroll
    for (int p = 0; p < 8; ++p) {
      uint2 d;
      d.x = cvtpk(av[p].x, av[p].y);
      d.y = cvtpk(av[p].z, av[p].w);
      *(uint2*)((char*)&sA[buf][0] + (p * 16 + ar) * 128 + awb) = d;
    }
  };
  auto compute = [&](int buf) {
    bf16x8 bfr[4][2];
    #pragma unroll
    for (int n = 0; n < 4; ++n) {
      const char* bb = (const char*)&sB[buf][0] + (wc*64 + n*16 + l15) * 128;
      bfr[n][0] = *(const bf16x8*)(bb + sw0);
      bfr[n][1] = *(const bf16x8*)(bb + sw1);
    }
    #pragma unroll
    for (int m = 0; m < 4; ++m) {
      const char* ab = (const char*)&sA[buf][0] + (wr*64 + m*16 + l15) * 128;
      bf16x8 a0 = *(const bf16x8*)(ab + sw0);
      bf16x8 a1 = *(const bf16x8*)(ab + sw1);
      #pragma unroll
      for (int n = 0; n < 4; ++n) {
        acc[m][n] = __builtin_amdgcn_mfma_f32_16x16x32_bf16(a0, bfr[n][0], acc[m][n], 0, 0, 0);
        acc[m][n] = __builtin_amdgcn_mfma_f32_16x16x32_bf16(a1, bfr[n][1], acc[m][n], 0, 0, 0);
      }
    }
  };

  auto body = [&](int k, float4* avC, float4* avL) {
    const int p = k & 1;
    const int kB = (k + 1 < NKS ? k + 1 : NKS - 1) * BK;
    const int kA = (k + 2 < NKS ? k + 2 : NKS - 1) * BK;
    stageB(p ^ 1, kB);                                // 4 glds (oldest)
    asm volatile("" ::: "memory");
    loadA(avL, kA);                                   // 8 loads (newest)
    asm volatile("" ::: "memory");
    storeA(p ^ 1, avC);                               // waits A(k+1) regs only
    compute(p);
    asm volatile("s_waitcnt vmcnt(8)" ::: "memory");  // drain 4 B-glds; 8 A fly on
    asm volatile("s_waitcnt lgkmcnt(0)" ::: "memory");
    __builtin_amdgcn_s_barrier();                     // ONE barrier per step
    __builtin_amdgcn_sched_barrier(0);
  };

  stageB(0, 0);
  asm volatile("" ::: "memory");
  loadA(avP, 0);
  asm volatile("" ::: "memory");
  loadA(avQ, BK);
  storeA(0, avP);
  __syncthreads();                                    // one-time full drain

  for (int k = 0; k < NKS; k += 2) {
    body(k,     avQ, avP);
    body(k + 1, avP, avQ);
  }

  float* xpo = xp + ((size_t)ksp * M_DIM + rowbase) * LAT + nrow0;
  #pragma unroll
  for (int m = 0; m < 4; ++m)
    #pragma unroll
    for (int n = 0; n < 4; ++n)
      #pragma unroll
      for (int j = 0; j < 4; ++j)
        xpo[(size_t)(wr*64 + m*16 + lc*4 + j) * LAT + wc*64 + n*16 + l15] = acc[m][n][j];
}

// ---------------- Kernel 3: MFMA-batched RNN, scratch-spill fixed.
// R9's VGPR_Count=92 proved xpP/xpQ lived in scratch (lambdas took float* ->
// alloca). Fix: 8 NAMED f32x4 banks, macro-expanded with compile-time indices
// only; launch_bounds(512,1) uncaps VGPRs (grid=4 blocks, occupancy moot).
__global__ void __launch_bounds__(512, 1) rnn_mfma_kernel(const float* __restrict__ xp,
                           const float* __restrict__ h0, const float* __restrict__ Wenc,
                           const float* __restrict__ bemb, const float* __restrict__ benc,
                           float* __restrict__ out) {
  const int tid = threadIdx.x;
  const int w = tid >> 6, lane = tid & 63;
  const int l15 = lane & 15, lc = lane >> 4;
  const int bb = blockIdx.x * 16;                  // batch base
  const int c0 = w*32 + l15, c1 = c0 + 16;         // latent cols (2 n-frags)
  const int rb = lc * 4;                           // C-row base (batch-local)

  __shared__ _Float16 hbuf[2][16 * 264];           // +8 f16 row pad

  f16x8 whf0[8], whf1[8];
  #pragma unroll
  for (int ks = 0; ks < 8; ++ks) {
    f16x8 w0, w1;
    #pragma unroll
    for (int j = 0; j < 8; ++j) {
      const int k = ks*32 + lc*8 + j;
      w0[j] = (_Float16)Wenc[(size_t)(EMB + k)*LAT + c0];
      w1[j] = (_Float16)Wenc[(size_t)(EMB + k)*LAT + c1];
    }
    whf0[ks] = w0; whf1[ks] = w1;
  }
  float bc0 = benc[c0], bc1 = benc[c1];
  for (int e = 0; e < 256; ++e) {
    float be = bemb[e];
    bc0 += be * Wenc[(size_t)e*LAT + c0];
    bc1 += be * Wenc[(size_t)e*LAT + c1];
  }
  #pragma unroll
  for (int j = 0; j < 4; ++j) {
    hbuf[0][(rb + j)*264 + c0] = (_Float16)h0[(size_t)(bb + rb + j)*LAT + c0];
    hbuf[0][(rb + j)*264 + c1] = (_Float16)h0[(size_t)(bb + rb + j)*LAT + c1];
  }
  __syncthreads();

  const size_t PO = (size_t)M_DIM * LAT;

  f32x4 xA0, xA1, xA2, xA3, xB0, xB1, xB2, xB3;    // named banks: never spill

#define LOADXP(R0, R1, R2, R3, t) {                                            \
    const size_t m0 = ((size_t)(t)*B_DIM + bb + rb) * LAT;                     \
    R0 = (f32x4){ xp[m0        +c0], xp[m0        +c0+PO], xp[m0        +c1], xp[m0        +c1+PO] }; \
    R1 = (f32x4){ xp[m0+  LAT  +c0], xp[m0+  LAT  +c0+PO], xp[m0+  LAT  +c1], xp[m0+  LAT  +c1+PO] }; \
    R2 = (f32x4){ xp[m0+2*LAT  +c0], xp[m0+2*LAT  +c0+PO], xp[m0+2*LAT  +c1], xp[m0+2*LAT  +c1+PO] }; \
    R3 = (f32x4){ xp[m0+3*LAT  +c0], xp[m0+3*LAT  +c0+PO], xp[m0+3*LAT  +c1], xp[m0+3*LAT  +c1+PO] }; \
  }

#define TANH1(j, R) {                                                          \
    float p0 = acc0[j] + bc0 + R.x + R.y;                                      \
    float p1 = acc1[j] + bc1 + R.z + R.w;                                      \
    float a0 = fabsf(p0),       a1 = fabsf(p1);                                \
    float e0 = __expf(-2.f*a0), e1 = __expf(-2.f*a1);                          \
    float r0 = __fdividef(1.f - e0, 1.f + e0);                                 \
    float r1 = __fdividef(1.f - e1, 1.f + e1);                                 \
    float h0v = (p0 < 0.f) ? -r0 : r0;                                         \
    float h1v = (p1 < 0.f) ? -r1 : r1;                                         \
    ob[(size_t)(j)*LAT + c0] = h0v;                                            \
    ob[(size_t)(j)*LAT + c1] = h1v;                                            \
    hn_[(rb + (j))*264 + c0] = (_Float16)h0v;                                  \
    hn_[(rb + (j))*264 + c1] = (_Float16)h1v;                                  \
  }

#define STEP(t, R0, R1, R2, R3) {                                              \
    const _Float16* hc = &hbuf[(t) & 1][0];                                    \
    f32x4 acc0 = (f32x4){0.f,0.f,0.f,0.f};                                     \
    f32x4 acc1 = (f32x4){0.f,0.f,0.f,0.f};                                     \
    _Pragma("unroll")                                                          \
    for (int ks = 0; ks < 8; ++ks) {                                           \
      f16x8 a = *(const f16x8*)(hc + l15*264 + ks*32 + lc*8);                  \
      acc0 = __builtin_amdgcn_mfma_f32_16x16x32_f16(a, whf0[ks], acc0, 0,0,0); \
      acc1 = __builtin_amdgcn_mfma_f32_16x16x32_f16(a, whf1[ks], acc1, 0,0,0); \
    }                                                                          \
    _Float16* hn_ = &hbuf[((t) + 1) & 1][0];                                   \
    float* ob = out + ((size_t)(t)*B_DIM + bb + rb) * LAT;                     \
    TANH1(0, R0) TANH1(1, R1) TANH1(2, R2) TANH1(3, R3)                        \
    const int tf = ((t) + 2 < T_DIM) ? (t) + 2 : T_DIM - 1;                    \
    LOADXP(R0, R1, R2, R3, tf);   /* refill: flies across barrier */           \
    __builtin_amdgcn_sched_barrier(0);                                         \
    asm volatile("s_waitcnt lgkmcnt(0)" ::: "memory");                         \
    __builtin_amdgcn_s_barrier();      /* vmcnt NOT drained */                 \
    __builtin_amdgcn_sched_barrier(0);                                         \
  }

  LOADXP(xA0, xA1, xA2, xA3, 0);
  LOADXP(xB0, xB1, xB2, xB3, 1);

  for (int t = 0; t < T_DIM; t += 2) {
    STEP(t,     xA0, xA1, xA2, xA3);
    STEP(t + 1, xB0, xB1, xB2, xB3);
  }
#undef STEP
#undef TANH1
#undef LOADXP
}

extern "C" void kernel_launch(void* const* d_in, const int* in_sizes, int n_in,
                              void* d_out, int out_size, void* d_ws, size_t ws_size,
                              hipStream_t stream) {
  const float* x    = (const float*)d_in[0];
  const float* h0   = (const float*)d_in[1];
  const float* Wemb = (const float*)d_in[2];
  const float* bemb = (const float*)d_in[3];
  const float* Wenc = (const float*)d_in[4];
  const float* benc = (const float*)d_in[5];
  float* out = (float*)d_out;

  ushort* wct = (ushort*)d_ws;                               // 4 MiB bf16 [256][8192]
  float*  xp  = (float*)((char*)d_ws + ((size_t)4 << 20));   // 2 x 16 MiB fp32 partials

  wct_kernel<<<256, 256, 0, stream>>>(Wemb, Wenc, wct);
  gemm2_kernel<<<512, 256, 0, stream>>>(x, wct, xp);
  rnn_mfma_kernel<<<4, 512, 0, stream>>>(xp, h0, Wenc, bemb, benc, out);
}